// Round 12
// baseline (36.337 us; speedup 1.0000x reference)
//
#include <hip/hip_runtime.h>
#include <math.h>

#define NSZ 512
#define MSZ 256
#define NPIX (6 * NSZ * NSZ)                      // 1,572,864 vertices
#define NQu  261121u                              // (NSZ-1)^2 quads per face
#define NQ2u 522242u                              // 2*NQu tris per face
#define NFACE 3133452                             // 6*2*NQu
#define F3TOT 9400356                             // NFACE*3 floats
#define NFT12 783363                              // F3TOT/12 (4 whole tris / thread)
#define TS 32                                     // output tile
#define HS 34                                     // vert halo
#define QS 33                                     // quad halo
#define NVB 1536                                  // 6*16*16 vert blocks
#define NFB ((NFT12 + 255) / 256)                 // 3061 faces blocks
#define GRID (NVB + NFB)

typedef __fp16 h2_t __attribute__((ext_vector_type(2)));

// ---- fast math helpers ----------------------------------------------------
__device__ inline float fast_rcp(float x) {
    float r = __builtin_amdgcn_rcpf(x);
    return r * (2.0f - x * r);
}
__device__ inline float fast_rsqrt(float d) {
    float r = __builtin_amdgcn_rsqf(d);
    return r * (1.5f - 0.5f * d * r * r);
}
__device__ inline float fast_sigmoid(float x) {
    float e = __builtin_amdgcn_exp2f(-1.442695040888963f * x);
    return fast_rcp(1.0f + e);
}
__device__ inline float lerpf(float a, float b, float w) {
    return __builtin_fmaf(w, b - a, a);
}
__device__ inline unsigned pkh2(float x, float y) {
    h2_t h = __builtin_amdgcn_cvt_pkrtz(x, y);
    return __builtin_bit_cast(unsigned, h);
}
__device__ inline float2 uph2(unsigned u) {
    h2_t h = __builtin_bit_cast(h2_t, u);
    return make_float2((float)h.x, (float)h.y);
}
__device__ inline unsigned pkadd(unsigned a, unsigned b) {   // v_pk_add_f16
    h2_t r = __builtin_bit_cast(h2_t, a) + __builtin_bit_cast(h2_t, b);
    return __builtin_bit_cast(unsigned, r);
}

__global__ __launch_bounds__(256) void k_all(const float* __restrict__ vrt,
                                             const float* __restrict__ nrm,
                                             const float* __restrict__ ps,
                                             float* __restrict__ out0,
                                             float* __restrict__ out1,
                                             float* __restrict__ out2) {
    // LDS: 13,872 + 3*4,356 = 26,940 B -> 5 blocks/CU
    __shared__ float sv[HS * HS * 3];         // displaced verts (halo), fp32
    __shared__ unsigned tnXY0[QS * QS];       // tri0 normal (x,y) fp16-packed
    __shared__ unsigned tnXY1[QS * QS];       // tri1 normal (x,y)
    __shared__ unsigned tnZZ [QS * QS];       // (z0, z1)

    int blk = blockIdx.x;

    if (blk >= NVB) {
        // ========== faces path: 12 floats = 4 whole tris / thread ==========
        int t = (blk - NVB) * 256 + threadIdx.x;
        if (t >= NFT12) return;
        unsigned tri = 4u * (unsigned)t;
        unsigned s   = tri / NQ2u;
        unsigned r1  = tri - s * NQ2u;
        unsigned ty  = (r1 >= NQu) ? 1u : 0u;
        unsigned qi  = r1 - ty * NQu;
        unsigned R   = qi / 511u;
        unsigned Q   = qi - R * 511u;

        unsigned a[4], tt[4];
        unsigned aq = Q, aR = R, aty = ty, as_ = s;
#pragma unroll
        for (int k = 0; k < 4; ++k) {
            a[k]  = (as_ << 18) + (aR << 9) + aq;
            tt[k] = aty;
            aq++;
            if (aq == 511u) {
                aq = 0u; aR++;
                if (aR == 511u) { aR = 0u; aty ^= 1u; if (aty == 0u) as_++; }
            }
        }
        float w[12];
#pragma unroll
        for (int k = 0; k < 4; ++k) {
            w[3*k + 0] = (float)(a[k] + (tt[k] ? 1u : 0u));
            w[3*k + 1] = (float)(a[k] + (tt[k] ? 513u : 1u));
            w[3*k + 2] = (float)(a[k] + 512u);
        }
        float4* o = (float4*)out1 + 3 * t;
        o[0] = make_float4(w[0], w[1], w[2],  w[3]);
        o[1] = make_float4(w[4], w[5], w[6],  w[7]);
        o[2] = make_float4(w[8], w[9], w[10], w[11]);
        return;
    }

    // ========== vert + normals path ==========
    int f   = blk >> 8;
    int tl  = blk & 255;
    int tr  = (tl >> 4) * TS;
    int tq  = (tl & 15) * TS;
    int fbm = f * (MSZ * MSZ);
    int fbn = f * (NSZ * NSZ);
    const float scale = 255.0f / 511.0f;

    // ---- phase 1: 34x34 halo of displaced verts -> sv, interior -> out0 ----
    // part A: 34 rows x 8 groups of 4 interior cols (pq = 1+4j..4+4j), 272 items
    // part B: 34 rows x 2 edge cols (pq = 0, 33), 68 items
    for (int p = threadIdx.x; p < 340; p += 256) {
        if (p < 272) {
            int pr = p >> 3, j = p & 7;
            int pq0 = 1 + 4 * j;
            int y  = tr + pr - 1;
            int yc = min(max(y, 0), NSZ - 1);
            int xbase = tq + pq0 - 1;             // in [tq, tq+28]; x+3 <= 511

            float cy = (float)yc * scale;
            int iy0 = min((int)cy, MSZ - 1);
            float wy = cy - (float)iy0;
            int   iya = min(iy0, MSZ - 2);
            float wya = (iy0 < MSZ - 1) ? wy : 1.0f;

            int ix0s[4]; float wxs[4];
#pragma unroll
            for (int i = 0; i < 4; ++i) {
                float cx = (float)(xbase + i) * scale;
                int ix0 = min((int)cx, MSZ - 1);
                ix0s[i] = ix0;
                wxs[i]  = (ix0 < MSZ - 1) ? (cx - (float)ix0) : 1.0f;
            }
            int c0 = min(min(ix0s[0], MSZ - 2), MSZ - 4);

            int g0 = (fbm + iya * MSZ + c0) * 3;    // 12 contiguous floats
            int g1 = g0 + MSZ * 3;

            float Yv[12], Yn[12];
#pragma unroll
            for (int c = 0; c < 12; ++c)
                Yv[c] = lerpf(vrt[g0 + c], vrt[g1 + c], wya);
#pragma unroll
            for (int c = 0; c < 12; ++c)
                Yn[c] = lerpf(nrm[g0 + c], nrm[g1 + c], wya);

            float ov[12];
#pragma unroll
            for (int i = 0; i < 4; ++i) {
                int li = min(ix0s[i], MSZ - 2) - c0;   // 0..2
                int b  = 3 * li;
                float wxa = wxs[i];
                float vx = lerpf(Yv[b + 0], Yv[b + 3], wxa);
                float vy = lerpf(Yv[b + 1], Yv[b + 4], wxa);
                float vz = lerpf(Yv[b + 2], Yv[b + 5], wxa);
                float nx = lerpf(Yn[b + 0], Yn[b + 3], wxa);
                float ny = lerpf(Yn[b + 1], Yn[b + 4], wxa);
                float nz = lerpf(Yn[b + 2], Yn[b + 5], wxa);
                float mag = __builtin_amdgcn_sqrtf(nx * nx + ny * ny + nz * nz);
                float sig = fast_sigmoid(ps[fbn + yc * NSZ + xbase + i]);
                float add = 0.5f * sig * mag;
                float ox = vx + add, oy = vy + add, oz = vz + add;
                int sb = (pr * HS + pq0 + i) * 3;
                sv[sb + 0] = ox; sv[sb + 1] = oy; sv[sb + 2] = oz;
                ov[3 * i + 0] = ox; ov[3 * i + 1] = oy; ov[3 * i + 2] = oz;
            }
            if (pr >= 1 && pr <= TS) {
                float4* o = (float4*)&out0[(size_t)(fbn + y * NSZ + xbase) * 3];
                o[0] = make_float4(ov[0], ov[1], ov[2],  ov[3]);
                o[1] = make_float4(ov[4], ov[5], ov[6],  ov[7]);
                o[2] = make_float4(ov[8], ov[9], ov[10], ov[11]);
            }
        } else {
            int e  = p - 272;
            int pr = e >> 1;
            int pq = (e & 1) ? (HS - 1) : 0;
            int y = tr + pr - 1, x = tq + pq - 1;
            int yc = min(max(y, 0), NSZ - 1);
            int xc = min(max(x, 0), NSZ - 1);

            float cy = (float)yc * scale;
            float cx = (float)xc * scale;
            int iy0 = min((int)cy, MSZ - 1);
            int ix0 = min((int)cx, MSZ - 1);
            float wy = cy - (float)iy0;
            float wx = cx - (float)ix0;
            int   iya = min(iy0, MSZ - 2);
            int   ixa = min(ix0, MSZ - 2);
            float wya = (iy0 < MSZ - 1) ? wy : 1.0f;
            float wxa = (ix0 < MSZ - 1) ? wx : 1.0f;

            int g0 = (fbm + iya * MSZ + ixa) * 3;
            int g1 = g0 + MSZ * 3;

            float vx, vy, vz, nx, ny, nz;
            {
                float a0 = vrt[g0], a1 = vrt[g0+1], a2 = vrt[g0+2];
                float a3 = vrt[g0+3], a4 = vrt[g0+4], a5 = vrt[g0+5];
                float b0 = vrt[g1], b1 = vrt[g1+1], b2 = vrt[g1+2];
                float b3 = vrt[g1+3], b4 = vrt[g1+4], b5 = vrt[g1+5];
                vx = lerpf(lerpf(a0, a3, wxa), lerpf(b0, b3, wxa), wya);
                vy = lerpf(lerpf(a1, a4, wxa), lerpf(b1, b4, wxa), wya);
                vz = lerpf(lerpf(a2, a5, wxa), lerpf(b2, b5, wxa), wya);
            }
            {
                float a0 = nrm[g0], a1 = nrm[g0+1], a2 = nrm[g0+2];
                float a3 = nrm[g0+3], a4 = nrm[g0+4], a5 = nrm[g0+5];
                float b0 = nrm[g1], b1 = nrm[g1+1], b2 = nrm[g1+2];
                float b3 = nrm[g1+3], b4 = nrm[g1+4], b5 = nrm[g1+5];
                nx = lerpf(lerpf(a0, a3, wxa), lerpf(b0, b3, wxa), wya);
                ny = lerpf(lerpf(a1, a4, wxa), lerpf(b1, b4, wxa), wya);
                nz = lerpf(lerpf(a2, a5, wxa), lerpf(b2, b5, wxa), wya);
            }
            float mag = __builtin_amdgcn_sqrtf(nx * nx + ny * ny + nz * nz);
            float sig = fast_sigmoid(ps[fbn + yc * NSZ + xc]);
            float add = 0.5f * sig * mag;
            int sb = (pr * HS + pq) * 3;
            sv[sb + 0] = vx + add; sv[sb + 1] = vy + add; sv[sb + 2] = vz + add;
        }
    }
    __syncthreads();

    // ---- phase 1.5: 33x33 quads' 2 tri unit normals, ONCE, fp16-packed ----
    for (int p = threadIdx.x; p < QS * QS; p += 256) {
        int Ri = p / QS, Qi = p - Ri * QS;
        int base = (Ri * HS + Qi) * 3;
        float Axx = sv[base + 0],        Axy = sv[base + 1],        Axz = sv[base + 2];
        float Bxx = sv[base + 3],        Bxy = sv[base + 4],        Bxz = sv[base + 5];
        float Cxx = sv[base + HS*3 + 0], Cxy = sv[base + HS*3 + 1], Cxz = sv[base + HS*3 + 2];
        float Dxx = sv[base + HS*3 + 3], Dxy = sv[base + HS*3 + 4], Dxz = sv[base + HS*3 + 5];

        float n0x, n0y, n0z;
        {   // tri0: (A, B, C)
            float e1x = Bxx - Axx, e1y = Bxy - Axy, e1z = Bxz - Axz;
            float e2x = Cxx - Axx, e2y = Cxy - Axy, e2z = Cxz - Axz;
            float cx = e1y * e2z - e1z * e2y;
            float cy = e1z * e2x - e1x * e2z;
            float cz = e1x * e2y - e1y * e2x;
            float d  = fmaxf(cx * cx + cy * cy + cz * cz, 1e-24f);
            float r  = fast_rsqrt(d);
            n0x = cx * r; n0y = cy * r; n0z = cz * r;
        }
        float n1x, n1y, n1z;
        {   // tri1: (B, D, C)
            float e1x = Dxx - Bxx, e1y = Dxy - Bxy, e1z = Dxz - Bxz;
            float e2x = Cxx - Bxx, e2y = Cxy - Bxy, e2z = Cxz - Bxz;
            float cx = e1y * e2z - e1z * e2y;
            float cy = e1z * e2x - e1x * e2z;
            float cz = e1x * e2y - e1y * e2x;
            float d  = fmaxf(cx * cx + cy * cy + cz * cz, 1e-24f);
            float r  = fast_rsqrt(d);
            n1x = cx * r; n1y = cy * r; n1z = cz * r;
        }
        tnXY0[p] = pkh2(n0x, n0y);
        tnXY1[p] = pkh2(n1x, n1y);
        tnZZ [p] = pkh2(n0z, n1z);
    }
    __syncthreads();

    // ---- phase 2: 4 consecutive vertices / thread, exactly 256 items ----
    float sg = (f == 1 || f == 2 || f == 5) ? 1.0f : -1.0f;
    {
        int r  = threadIdx.x >> 3;            // 0..31
        int q0 = (threadIdx.x & 7) * 4;       // 0,4,..,28
        int b0 = r * QS + q0;                 // row r, cols q0..q0+4
        int b1 = b0 + QS;                     // row r+1

        unsigned t0r0[5], t0r1[5], t1r0[5], t1r1[5], zr0[5], zr1[5];
#pragma unroll
        for (int c = 0; c < 5; ++c) {
            t0r0[c] = tnXY0[b0 + c];
            t0r1[c] = tnXY0[b1 + c];
            t1r0[c] = tnXY1[b0 + c];
            t1r1[c] = tnXY1[b1 + c];
            zr0[c]  = tnZZ [b0 + c];
            zr1[c]  = tnZZ [b1 + c];
        }

        float ov[12];
#pragma unroll
        for (int i = 0; i < 4; ++i) {
            // xy: tn0 @ q11(r1,i+1), q10(r1,i), q01(r0,i+1); tn1 @ q10, q00(r0,i), q01
            unsigned axy = pkadd(pkadd(pkadd(t0r1[i+1], t0r1[i]),
                                       pkadd(t0r0[i+1], t1r1[i])),
                                 pkadd(t1r0[i],  t1r0[i+1]));
            float2 xy = uph2(axy);
            // z: z0 @ q11,q10,q01 ; z1 @ q10,q00,q01
            unsigned S = pkadd(zr1[i], zr0[i+1]);
            float2 s1 = uph2(pkadd(S, zr1[i+1]));
            float2 s2 = uph2(pkadd(S, zr0[i]));
            float az = s1.x + s2.y;

            float d  = fmaxf(xy.x * xy.x + xy.y * xy.y + az * az, 1e-24f);
            float rs = fast_rsqrt(d) * sg;
            ov[3*i + 0] = xy.x * rs;
            ov[3*i + 1] = xy.y * rs;
            ov[3*i + 2] = az  * rs;
        }
        float4* o = (float4*)&out2[(size_t)(fbn + (tr + r) * NSZ + tq + q0) * 3];
        o[0] = make_float4(ov[0], ov[1], ov[2],  ov[3]);
        o[1] = make_float4(ov[4], ov[5], ov[6],  ov[7]);
        o[2] = make_float4(ov[8], ov[9], ov[10], ov[11]);
    }
}

extern "C" void kernel_launch(void* const* d_in, const int* in_sizes, int n_in,
                              void* d_out, int out_size, void* d_ws, size_t ws_size,
                              hipStream_t stream) {
    const float* vrt = (const float*)d_in[0];
    const float* nrm = (const float*)d_in[1];
    const float* ps  = (const float*)d_in[2];

    float* out0 = (float*)d_out;                 // vert:    6*512*512*3
    float* out1 = out0 + (size_t)NPIX * 3;       // faces:   NFACE*3
    float* out2 = out1 + (size_t)F3TOT;          // normals: 6*512*512*3

    k_all<<<GRID, 256, 0, stream>>>(vrt, nrm, ps, out0, out1, out2);
}

// Round 13
// 33.021 us; speedup vs baseline: 1.1004x; 1.1004x over previous
//
#include <hip/hip_runtime.h>
#include <math.h>

#define NSZ 512
#define MSZ 256
#define NPIX (6 * NSZ * NSZ)                      // 1,572,864 vertices
#define NQu  261121u                              // (NSZ-1)^2 quads per face
#define NQ2u 522242u                              // 2*NQu tris per face
#define NFACE 3133452                             // 6*2*NQu
#define F3TOT 9400356                             // NFACE*3 floats
#define NFT12 783363                              // F3TOT/12 (4 whole tris / thread)
#define TS 32                                     // output tile
#define HS 34                                     // vert halo
#define QS 33                                     // quad halo
#define NVB 1536                                  // 6*16*16 vert blocks
#define NFB ((NFT12 + 255) / 256)                 // 3061 faces blocks
#define GRID (NVB + NFB)

typedef __fp16 h2_t __attribute__((ext_vector_type(2)));

// ---- fast math helpers ----------------------------------------------------
__device__ inline float fast_rcp(float x) {
    float r = __builtin_amdgcn_rcpf(x);
    return r * (2.0f - x * r);
}
__device__ inline float fast_rsqrt(float d) {
    float r = __builtin_amdgcn_rsqf(d);
    return r * (1.5f - 0.5f * d * r * r);
}
__device__ inline float fast_sigmoid(float x) {
    float e = __builtin_amdgcn_exp2f(-1.442695040888963f * x);
    return fast_rcp(1.0f + e);
}
__device__ inline float lerpf(float a, float b, float w) {
    return __builtin_fmaf(w, b - a, a);
}
__device__ inline unsigned pkh2(float x, float y) {
    h2_t h = __builtin_amdgcn_cvt_pkrtz(x, y);
    return __builtin_bit_cast(unsigned, h);
}
__device__ inline float2 uph2(unsigned u) {
    h2_t h = __builtin_bit_cast(h2_t, u);
    return make_float2((float)h.x, (float)h.y);
}
__device__ inline unsigned pkadd(unsigned a, unsigned b) {   // v_pk_add_f16
    h2_t r = __builtin_bit_cast(h2_t, a) + __builtin_bit_cast(h2_t, b);
    return __builtin_bit_cast(unsigned, r);
}
// 3-way select with COMPILE-TIME operand indices (2 v_cndmask, no scratch)
__device__ inline float sel3(int d, float a, float b, float c) {
    float r = (d == 1) ? b : a;
    return (d == 2) ? c : r;
}

__global__ __launch_bounds__(256) void k_all(const float* __restrict__ vrt,
                                             const float* __restrict__ nrm,
                                             const float* __restrict__ ps,
                                             float* __restrict__ out0,
                                             float* __restrict__ out1,
                                             float* __restrict__ out2) {
    // LDS: 13,872 + 3*4,356 = 26,940 B
    __shared__ float sv[HS * HS * 3];         // displaced verts (halo), fp32
    __shared__ unsigned tnXY0[QS * QS];       // tri0 normal (x,y) fp16-packed
    __shared__ unsigned tnXY1[QS * QS];       // tri1 normal (x,y)
    __shared__ unsigned tnZZ [QS * QS];       // (z0, z1)

    int blk = blockIdx.x;

    if (blk >= NVB) {
        // ========== faces path: 12 floats = 4 whole tris / thread ==========
        int t = (blk - NVB) * 256 + threadIdx.x;
        if (t >= NFT12) return;
        unsigned tri = 4u * (unsigned)t;
        unsigned s   = tri / NQ2u;
        unsigned r1  = tri - s * NQ2u;
        unsigned ty  = (r1 >= NQu) ? 1u : 0u;
        unsigned qi  = r1 - ty * NQu;
        unsigned R   = qi / 511u;
        unsigned Q   = qi - R * 511u;

        unsigned a[4], tt[4];
        unsigned aq = Q, aR = R, aty = ty, as_ = s;
#pragma unroll
        for (int k = 0; k < 4; ++k) {
            a[k]  = (as_ << 18) + (aR << 9) + aq;
            tt[k] = aty;
            aq++;
            if (aq == 511u) {
                aq = 0u; aR++;
                if (aR == 511u) { aR = 0u; aty ^= 1u; if (aty == 0u) as_++; }
            }
        }
        float w[12];
#pragma unroll
        for (int k = 0; k < 4; ++k) {
            w[3*k + 0] = (float)(a[k] + (tt[k] ? 1u : 0u));
            w[3*k + 1] = (float)(a[k] + (tt[k] ? 513u : 1u));
            w[3*k + 2] = (float)(a[k] + 512u);
        }
        float4* o = (float4*)out1 + 3 * t;
        o[0] = make_float4(w[0], w[1], w[2],  w[3]);
        o[1] = make_float4(w[4], w[5], w[6],  w[7]);
        o[2] = make_float4(w[8], w[9], w[10], w[11]);
        return;
    }

    // ========== vert + normals path ==========
    int f   = blk >> 8;
    int tl  = blk & 255;
    int tr  = (tl >> 4) * TS;
    int tq  = (tl & 15) * TS;
    int fbm = f * (MSZ * MSZ);
    int fbn = f * (NSZ * NSZ);
    const float scale = 255.0f / 511.0f;

    // ---- phase 1: 34x34 halo -> sv, interior -> out0 ----
    // part A: 34 rows x 8 groups of 4 interior cols (pq = 1+4j), 272 items
    // part B: 34 rows x 2 edge cols (pq = 0, 33), 68 items
    for (int p = threadIdx.x; p < 340; p += 256) {
        if (p < 272) {
            int pr = p >> 3, j = p & 7;
            int pq0 = 1 + 4 * j;
            int y  = tr + pr - 1;
            int yc = min(max(y, 0), NSZ - 1);
            int xbase = tq + pq0 - 1;            // 4-aligned, in [0, 508]

            float cy = (float)yc * scale;
            int iy0 = min((int)cy, MSZ - 1);
            float wy = cy - (float)iy0;
            int   iya = min(iy0, MSZ - 2);
            float wya = (iy0 < MSZ - 1) ? wy : 1.0f;

            int d0, d1, d2, d3;
            float w0, w1, w2, w3;
            int c0;
            {
                float cx0 = (float)(xbase + 0) * scale;
                float cx1 = (float)(xbase + 1) * scale;
                float cx2 = (float)(xbase + 2) * scale;
                float cx3 = (float)(xbase + 3) * scale;
                int i0 = min((int)cx0, MSZ - 1);
                int i1 = min((int)cx1, MSZ - 1);
                int i2 = min((int)cx2, MSZ - 1);
                int i3 = min((int)cx3, MSZ - 1);
                w0 = (i0 < MSZ - 1) ? cx0 - (float)i0 : 1.0f;
                w1 = (i1 < MSZ - 1) ? cx1 - (float)i1 : 1.0f;
                w2 = (i2 < MSZ - 1) ? cx2 - (float)i2 : 1.0f;
                w3 = (i3 < MSZ - 1) ? cx3 - (float)i3 : 1.0f;
                int b0 = min(i0, MSZ - 2), b1 = min(i1, MSZ - 2);
                int b2 = min(i2, MSZ - 2), b3 = min(i3, MSZ - 2);
                c0 = min(b0, MSZ - 4);           // texels c0..c0+3 in-row
                d0 = b0 - c0; d1 = b1 - c0; d2 = b2 - c0; d3 = b3 - c0;  // 0..2
            }

            int g0 = (fbm + iya * MSZ + c0) * 3;   // 12 contiguous floats
            int g1 = g0 + MSZ * 3;

            // y-lerp of 4 texels x 3 ch, both tensors (static indices only)
            float Yv0 = lerpf(vrt[g0+0],  vrt[g1+0],  wya);
            float Yv1 = lerpf(vrt[g0+1],  vrt[g1+1],  wya);
            float Yv2 = lerpf(vrt[g0+2],  vrt[g1+2],  wya);
            float Yv3 = lerpf(vrt[g0+3],  vrt[g1+3],  wya);
            float Yv4 = lerpf(vrt[g0+4],  vrt[g1+4],  wya);
            float Yv5 = lerpf(vrt[g0+5],  vrt[g1+5],  wya);
            float Yv6 = lerpf(vrt[g0+6],  vrt[g1+6],  wya);
            float Yv7 = lerpf(vrt[g0+7],  vrt[g1+7],  wya);
            float Yv8 = lerpf(vrt[g0+8],  vrt[g1+8],  wya);
            float Yv9 = lerpf(vrt[g0+9],  vrt[g1+9],  wya);
            float Yv10= lerpf(vrt[g0+10], vrt[g1+10], wya);
            float Yv11= lerpf(vrt[g0+11], vrt[g1+11], wya);
            float Yn0 = lerpf(nrm[g0+0],  nrm[g1+0],  wya);
            float Yn1 = lerpf(nrm[g0+1],  nrm[g1+1],  wya);
            float Yn2 = lerpf(nrm[g0+2],  nrm[g1+2],  wya);
            float Yn3 = lerpf(nrm[g0+3],  nrm[g1+3],  wya);
            float Yn4 = lerpf(nrm[g0+4],  nrm[g1+4],  wya);
            float Yn5 = lerpf(nrm[g0+5],  nrm[g1+5],  wya);
            float Yn6 = lerpf(nrm[g0+6],  nrm[g1+6],  wya);
            float Yn7 = lerpf(nrm[g0+7],  nrm[g1+7],  wya);
            float Yn8 = lerpf(nrm[g0+8],  nrm[g1+8],  wya);
            float Yn9 = lerpf(nrm[g0+9],  nrm[g1+9],  wya);
            float Yn10= lerpf(nrm[g0+10], nrm[g1+10], wya);
            float Yn11= lerpf(nrm[g0+11], nrm[g1+11], wya);

            float4 psv = *(const float4*)&ps[fbn + yc * NSZ + xbase];  // 16B-aligned

            float ov[12];
            int dd[4] = {d0, d1, d2, d3};
            float ww[4] = {w0, w1, w2, w3};
            float pp[4] = {psv.x, psv.y, psv.z, psv.w};
#pragma unroll
            for (int i = 0; i < 4; ++i) {
                int   d  = dd[i];
                float wxa = ww[i];
                float vx = lerpf(sel3(d, Yv0, Yv3, Yv6), sel3(d, Yv3, Yv6, Yv9),  wxa);
                float vy = lerpf(sel3(d, Yv1, Yv4, Yv7), sel3(d, Yv4, Yv7, Yv10), wxa);
                float vz = lerpf(sel3(d, Yv2, Yv5, Yv8), sel3(d, Yv5, Yv8, Yv11), wxa);
                float nx = lerpf(sel3(d, Yn0, Yn3, Yn6), sel3(d, Yn3, Yn6, Yn9),  wxa);
                float ny = lerpf(sel3(d, Yn1, Yn4, Yn7), sel3(d, Yn4, Yn7, Yn10), wxa);
                float nz = lerpf(sel3(d, Yn2, Yn5, Yn8), sel3(d, Yn5, Yn8, Yn11), wxa);
                float mag = __builtin_amdgcn_sqrtf(nx * nx + ny * ny + nz * nz);
                float add = 0.5f * fast_sigmoid(pp[i]) * mag;
                float ox = vx + add, oy = vy + add, oz = vz + add;
                int sb = (pr * HS + pq0 + i) * 3;
                sv[sb + 0] = ox; sv[sb + 1] = oy; sv[sb + 2] = oz;
                ov[3*i + 0] = ox; ov[3*i + 1] = oy; ov[3*i + 2] = oz;
            }
            if (pr >= 1 && pr <= TS) {
                float4* o = (float4*)&out0[(size_t)(fbn + y * NSZ + xbase) * 3];
                o[0] = make_float4(ov[0], ov[1], ov[2],  ov[3]);
                o[1] = make_float4(ov[4], ov[5], ov[6],  ov[7]);
                o[2] = make_float4(ov[8], ov[9], ov[10], ov[11]);
            }
        } else {
            int e  = p - 272;
            int pr = e >> 1;
            int pq = (e & 1) ? (HS - 1) : 0;
            int y = tr + pr - 1, x = tq + pq - 1;
            int yc = min(max(y, 0), NSZ - 1);
            int xc = min(max(x, 0), NSZ - 1);

            float cy = (float)yc * scale;
            float cx = (float)xc * scale;
            int iy0 = min((int)cy, MSZ - 1);
            int ix0 = min((int)cx, MSZ - 1);
            float wy = cy - (float)iy0;
            float wx = cx - (float)ix0;
            int   iya = min(iy0, MSZ - 2);
            int   ixa = min(ix0, MSZ - 2);
            float wya = (iy0 < MSZ - 1) ? wy : 1.0f;
            float wxa = (ix0 < MSZ - 1) ? wx : 1.0f;

            int g0 = (fbm + iya * MSZ + ixa) * 3;
            int g1 = g0 + MSZ * 3;

            float vx, vy, vz, nx, ny, nz;
            {
                float a0 = vrt[g0], a1 = vrt[g0+1], a2 = vrt[g0+2];
                float a3 = vrt[g0+3], a4 = vrt[g0+4], a5 = vrt[g0+5];
                float b0 = vrt[g1], b1 = vrt[g1+1], b2 = vrt[g1+2];
                float b3 = vrt[g1+3], b4 = vrt[g1+4], b5 = vrt[g1+5];
                vx = lerpf(lerpf(a0, b0, wya), lerpf(a3, b3, wya), wxa);
                vy = lerpf(lerpf(a1, b1, wya), lerpf(a4, b4, wya), wxa);
                vz = lerpf(lerpf(a2, b2, wya), lerpf(a5, b5, wya), wxa);
            }
            {
                float a0 = nrm[g0], a1 = nrm[g0+1], a2 = nrm[g0+2];
                float a3 = nrm[g0+3], a4 = nrm[g0+4], a5 = nrm[g0+5];
                float b0 = nrm[g1], b1 = nrm[g1+1], b2 = nrm[g1+2];
                float b3 = nrm[g1+3], b4 = nrm[g1+4], b5 = nrm[g1+5];
                nx = lerpf(lerpf(a0, b0, wya), lerpf(a3, b3, wya), wxa);
                ny = lerpf(lerpf(a1, b1, wya), lerpf(a4, b4, wya), wxa);
                nz = lerpf(lerpf(a2, b2, wya), lerpf(a5, b5, wya), wxa);
            }
            float mag = __builtin_amdgcn_sqrtf(nx * nx + ny * ny + nz * nz);
            float sig = fast_sigmoid(ps[fbn + yc * NSZ + xc]);
            float add = 0.5f * sig * mag;
            int sb = (pr * HS + pq) * 3;
            sv[sb + 0] = vx + add; sv[sb + 1] = vy + add; sv[sb + 2] = vz + add;
        }
    }
    __syncthreads();

    // ---- phase 1.5: 33x33 quads' 2 tri unit normals, ONCE, fp16-packed ----
    for (int p = threadIdx.x; p < QS * QS; p += 256) {
        int Ri = p / QS, Qi = p - Ri * QS;
        int base = (Ri * HS + Qi) * 3;
        float Axx = sv[base + 0],        Axy = sv[base + 1],        Axz = sv[base + 2];
        float Bxx = sv[base + 3],        Bxy = sv[base + 4],        Bxz = sv[base + 5];
        float Cxx = sv[base + HS*3 + 0], Cxy = sv[base + HS*3 + 1], Cxz = sv[base + HS*3 + 2];
        float Dxx = sv[base + HS*3 + 3], Dxy = sv[base + HS*3 + 4], Dxz = sv[base + HS*3 + 5];

        float n0x, n0y, n0z;
        {   // tri0: (A, B, C)
            float e1x = Bxx - Axx, e1y = Bxy - Axy, e1z = Bxz - Axz;
            float e2x = Cxx - Axx, e2y = Cxy - Axy, e2z = Cxz - Axz;
            float cx = e1y * e2z - e1z * e2y;
            float cy = e1z * e2x - e1x * e2z;
            float cz = e1x * e2y - e1y * e2x;
            float d  = fmaxf(cx * cx + cy * cy + cz * cz, 1e-24f);
            float r  = fast_rsqrt(d);
            n0x = cx * r; n0y = cy * r; n0z = cz * r;
        }
        float n1x, n1y, n1z;
        {   // tri1: (B, D, C)
            float e1x = Dxx - Bxx, e1y = Dxy - Bxy, e1z = Dxz - Bxz;
            float e2x = Cxx - Bxx, e2y = Cxy - Bxy, e2z = Cxz - Bxz;
            float cx = e1y * e2z - e1z * e2y;
            float cy = e1z * e2x - e1x * e2z;
            float cz = e1x * e2y - e1y * e2x;
            float d  = fmaxf(cx * cx + cy * cy + cz * cz, 1e-24f);
            float r  = fast_rsqrt(d);
            n1x = cx * r; n1y = cy * r; n1z = cz * r;
        }
        tnXY0[p] = pkh2(n0x, n0y);
        tnXY1[p] = pkh2(n1x, n1y);
        tnZZ [p] = pkh2(n0z, n1z);
    }
    __syncthreads();

    // ---- phase 2: 4 consecutive vertices / thread, exactly 256 items ----
    float sg = (f == 1 || f == 2 || f == 5) ? 1.0f : -1.0f;
    {
        int r  = threadIdx.x >> 3;            // 0..31
        int q0 = (threadIdx.x & 7) * 4;       // 0,4,..,28
        int b0 = r * QS + q0;
        int b1 = b0 + QS;

        unsigned t0r0[5], t0r1[5], t1r0[5], t1r1[5], zr0[5], zr1[5];
#pragma unroll
        for (int c = 0; c < 5; ++c) {
            t0r0[c] = tnXY0[b0 + c];
            t0r1[c] = tnXY0[b1 + c];
            t1r0[c] = tnXY1[b0 + c];
            t1r1[c] = tnXY1[b1 + c];
            zr0[c]  = tnZZ [b0 + c];
            zr1[c]  = tnZZ [b1 + c];
        }

        float ov[12];
#pragma unroll
        for (int i = 0; i < 4; ++i) {
            unsigned axy = pkadd(pkadd(pkadd(t0r1[i+1], t0r1[i]),
                                       pkadd(t0r0[i+1], t1r1[i])),
                                 pkadd(t1r0[i],  t1r0[i+1]));
            float2 xy = uph2(axy);
            unsigned S = pkadd(zr1[i], zr0[i+1]);
            float2 s1 = uph2(pkadd(S, zr1[i+1]));
            float2 s2 = uph2(pkadd(S, zr0[i]));
            float az = s1.x + s2.y;

            float d  = fmaxf(xy.x * xy.x + xy.y * xy.y + az * az, 1e-24f);
            float rs = fast_rsqrt(d) * sg;
            ov[3*i + 0] = xy.x * rs;
            ov[3*i + 1] = xy.y * rs;
            ov[3*i + 2] = az  * rs;
        }
        float4* o = (float4*)&out2[(size_t)(fbn + (tr + r) * NSZ + tq + q0) * 3];
        o[0] = make_float4(ov[0], ov[1], ov[2],  ov[3]);
        o[1] = make_float4(ov[4], ov[5], ov[6],  ov[7]);
        o[2] = make_float4(ov[8], ov[9], ov[10], ov[11]);
    }
}

extern "C" void kernel_launch(void* const* d_in, const int* in_sizes, int n_in,
                              void* d_out, int out_size, void* d_ws, size_t ws_size,
                              hipStream_t stream) {
    const float* vrt = (const float*)d_in[0];
    const float* nrm = (const float*)d_in[1];
    const float* ps  = (const float*)d_in[2];

    float* out0 = (float*)d_out;                 // vert:    6*512*512*3
    float* out1 = out0 + (size_t)NPIX * 3;       // faces:   NFACE*3
    float* out2 = out1 + (size_t)F3TOT;          // normals: 6*512*512*3

    k_all<<<GRID, 256, 0, stream>>>(vrt, nrm, ps, out0, out1, out2);
}

// Round 14
// 28.937 us; speedup vs baseline: 1.2557x; 1.1411x over previous
//
#include <hip/hip_runtime.h>
#include <math.h>

#define NSZ 512
#define MSZ 256
#define NPIX (6 * NSZ * NSZ)                      // 1,572,864 vertices
#define NQu  261121u                              // (NSZ-1)^2 quads per face
#define NQ2u 522242u                              // 2*NQu tris per face
#define NFACE 3133452                             // 6*2*NQu
#define F3TOT 9400356                             // NFACE*3 floats
#define NFT12 783363                              // F3TOT/12 (4 whole tris / thread)
#define TS 32                                     // output tile
#define HS 34                                     // vert halo
#define QS 33                                     // quad halo
#define NVB 1536                                  // 6*16*16 vert blocks
#define GRID (NVB * 3)                            // [v, f, f] triples = 4608 blocks

typedef __fp16 h2_t __attribute__((ext_vector_type(2)));

// ---- fast math helpers (raw HW op + 1 Newton step) -----------------------
__device__ inline float fast_rcp(float x) {
    float r = __builtin_amdgcn_rcpf(x);
    return r * (2.0f - x * r);
}
__device__ inline float fast_rsqrt(float d) {
    float r = __builtin_amdgcn_rsqf(d);
    return r * (1.5f - 0.5f * d * r * r);
}
__device__ inline float fast_sigmoid(float x) {
    float e = __builtin_amdgcn_exp2f(-1.442695040888963f * x);
    return fast_rcp(1.0f + e);
}
__device__ inline float lerpf(float a, float b, float w) {
    return __builtin_fmaf(w, b - a, a);
}
// pack two floats to half2 bits (one v_cvt_pkrtz_f16_f32)
__device__ inline unsigned pkh2(float x, float y) {
    h2_t h = __builtin_amdgcn_cvt_pkrtz(x, y);
    return __builtin_bit_cast(unsigned, h);
}
__device__ inline float2 uph2(unsigned u) {
    h2_t h = __builtin_bit_cast(h2_t, u);
    return make_float2((float)h.x, (float)h.y);
}

__global__ __launch_bounds__(256) void k_all(const float* __restrict__ vrt,
                                             const float* __restrict__ nrm,
                                             const float* __restrict__ ps,
                                             float* __restrict__ out0,
                                             float* __restrict__ out1,
                                             float* __restrict__ out2) {
    // LDS: 13,872 + 3*4,356 = 26,940 B (same as R10 best)
    __shared__ float sv[HS * HS * 3];         // displaced verts (halo), fp32
    __shared__ unsigned tnXY0[QS * QS];       // tri0 normal (x,y) fp16-packed
    __shared__ unsigned tnXY1[QS * QS];       // tri1 normal (x,y)
    __shared__ unsigned tnZZ [QS * QS];       // (z0, z1)

    int blk = blockIdx.x;
    int grp = blk / 3;
    int pos = blk - grp * 3;

    if (pos != 0) {
        // ========== faces path: 12 floats = 4 whole tris / thread ==========
        // interleaved with vert blocks so the write stream overlaps compute
        int t = (grp * 2 + (pos - 1)) * 256 + threadIdx.x;
        if (t >= NFT12) return;
        unsigned tri = 4u * (unsigned)t;          // j = 12t -> tri = 4t
        unsigned s   = tri / NQ2u;
        unsigned r1  = tri - s * NQ2u;
        unsigned ty  = (r1 >= NQu) ? 1u : 0u;
        unsigned qi  = r1 - ty * NQu;
        unsigned R   = qi / 511u;
        unsigned Q   = qi - R * 511u;

        unsigned a[4], tt[4];
        unsigned aq = Q, aR = R, aty = ty, as_ = s;
#pragma unroll
        for (int k = 0; k < 4; ++k) {
            a[k]  = (as_ << 18) + (aR << 9) + aq;
            tt[k] = aty;
            aq++;
            if (aq == 511u) {
                aq = 0u; aR++;
                if (aR == 511u) { aR = 0u; aty ^= 1u; if (aty == 0u) as_++; }
            }
        }
        float w[12];
#pragma unroll
        for (int k = 0; k < 4; ++k) {
            w[3*k + 0] = (float)(a[k] + (tt[k] ? 1u : 0u));
            w[3*k + 1] = (float)(a[k] + (tt[k] ? 513u : 1u));
            w[3*k + 2] = (float)(a[k] + 512u);
        }
        float4* o = (float4*)out1 + 3 * t;
        o[0] = make_float4(w[0], w[1], w[2],  w[3]);
        o[1] = make_float4(w[4], w[5], w[6],  w[7]);
        o[2] = make_float4(w[8], w[9], w[10], w[11]);
        return;
    }

    // ========== vert + normals path (identical to R10 best) ==========
    int f   = grp >> 8;
    int tl  = grp & 255;
    int tr  = (tl >> 4) * TS;
    int tq  = (tl & 15) * TS;
    int fbm = f * (MSZ * MSZ);
    int fbn = f * (NSZ * NSZ);

    // phase 1: 34x34 halo of displaced verts -> sv (+ write interior to out0)
    const float scale = 255.0f / 511.0f;
    for (int p = threadIdx.x; p < HS * HS; p += 256) {
        int pr = p / HS, pq = p - pr * HS;
        int y = tr + pr - 1, x = tq + pq - 1;
        int yc = min(max(y, 0), NSZ - 1);
        int xc = min(max(x, 0), NSZ - 1);

        float cy = (float)yc * scale;
        float cx = (float)xc * scale;
        int iy0 = min((int)cy, MSZ - 1);
        int ix0 = min((int)cx, MSZ - 1);
        float wy = cy - (float)iy0;
        float wx = cx - (float)ix0;
        // contiguous-pair base with edge-exact weight remap
        int   iya = min(iy0, MSZ - 2);
        int   ixa = min(ix0, MSZ - 2);
        float wya = (iy0 < MSZ - 1) ? wy : 1.0f;
        float wxa = (ix0 < MSZ - 1) ? wx : 1.0f;

        int g0 = (fbm + iya * MSZ + ixa) * 3;     // row iya: 6 contiguous floats
        int g1 = g0 + MSZ * 3;                     // row iya+1

        float vx, vy, vz;
        {
            float a0 = vrt[g0], a1 = vrt[g0+1], a2 = vrt[g0+2];
            float a3 = vrt[g0+3], a4 = vrt[g0+4], a5 = vrt[g0+5];
            float b0 = vrt[g1], b1 = vrt[g1+1], b2 = vrt[g1+2];
            float b3 = vrt[g1+3], b4 = vrt[g1+4], b5 = vrt[g1+5];
            vx = lerpf(lerpf(a0, a3, wxa), lerpf(b0, b3, wxa), wya);
            vy = lerpf(lerpf(a1, a4, wxa), lerpf(b1, b4, wxa), wya);
            vz = lerpf(lerpf(a2, a5, wxa), lerpf(b2, b5, wxa), wya);
        }
        float nx, ny, nz;
        {
            float a0 = nrm[g0], a1 = nrm[g0+1], a2 = nrm[g0+2];
            float a3 = nrm[g0+3], a4 = nrm[g0+4], a5 = nrm[g0+5];
            float b0 = nrm[g1], b1 = nrm[g1+1], b2 = nrm[g1+2];
            float b3 = nrm[g1+3], b4 = nrm[g1+4], b5 = nrm[g1+5];
            nx = lerpf(lerpf(a0, a3, wxa), lerpf(b0, b3, wxa), wya);
            ny = lerpf(lerpf(a1, a4, wxa), lerpf(b1, b4, wxa), wya);
            nz = lerpf(lerpf(a2, a5, wxa), lerpf(b2, b5, wxa), wya);
        }

        float mag = __builtin_amdgcn_sqrtf(nx * nx + ny * ny + nz * nz);
        float sig = fast_sigmoid(ps[fbn + yc * NSZ + xc]);
        float add = 0.5f * sig * mag;
        float ox = vx + add, oy = vy + add, oz = vz + add;

        sv[p * 3 + 0] = ox;
        sv[p * 3 + 1] = oy;
        sv[p * 3 + 2] = oz;
        if (pr >= 1 && pr <= TS && pq >= 1 && pq <= TS) {
            int gi = (fbn + y * NSZ + x) * 3;
            out0[gi + 0] = ox;
            out0[gi + 1] = oy;
            out0[gi + 2] = oz;
        }
    }
    __syncthreads();

    // phase 1.5: unit normals of 33x33 quads' 2 tris, ONCE, fp16-packed.
    for (int p = threadIdx.x; p < QS * QS; p += 256) {
        int Ri = p / QS, Qi = p - Ri * QS;
        int base = (Ri * HS + Qi) * 3;
        float Axx = sv[base + 0],        Axy = sv[base + 1],        Axz = sv[base + 2];
        float Bxx = sv[base + 3],        Bxy = sv[base + 4],        Bxz = sv[base + 5];
        float Cxx = sv[base + HS*3 + 0], Cxy = sv[base + HS*3 + 1], Cxz = sv[base + HS*3 + 2];
        float Dxx = sv[base + HS*3 + 3], Dxy = sv[base + HS*3 + 4], Dxz = sv[base + HS*3 + 5];

        float n0x, n0y, n0z;
        {   // tri0: (A, B, C)
            float e1x = Bxx - Axx, e1y = Bxy - Axy, e1z = Bxz - Axz;
            float e2x = Cxx - Axx, e2y = Cxy - Axy, e2z = Cxz - Axz;
            float cx = e1y * e2z - e1z * e2y;
            float cy = e1z * e2x - e1x * e2z;
            float cz = e1x * e2y - e1y * e2x;
            float d  = fmaxf(cx * cx + cy * cy + cz * cz, 1e-24f);
            float r  = fast_rsqrt(d);
            n0x = cx * r; n0y = cy * r; n0z = cz * r;
        }
        float n1x, n1y, n1z;
        {   // tri1: (B, D, C)
            float e1x = Dxx - Bxx, e1y = Dxy - Bxy, e1z = Dxz - Bxz;
            float e2x = Cxx - Bxx, e2y = Cxy - Bxy, e2z = Cxz - Bxz;
            float cx = e1y * e2z - e1z * e2y;
            float cy = e1z * e2x - e1x * e2z;
            float cz = e1x * e2y - e1y * e2x;
            float d  = fmaxf(cx * cx + cy * cy + cz * cz, 1e-24f);
            float r  = fast_rsqrt(d);
            n1x = cx * r; n1y = cy * r; n1z = cz * r;
        }
        tnXY0[p] = pkh2(n0x, n0y);
        tnXY1[p] = pkh2(n1x, n1y);
        tnZZ [p] = pkh2(n0z, n1z);
    }
    __syncthreads();

    // phase 2: vertex normal = normalize( sum of 6 adjacent tri normals )
    float sg = (f == 1 || f == 2 || f == 5) ? 1.0f : -1.0f;
    for (int p = threadIdx.x; p < TS * TS; p += 256) {
        int r = p >> 5, q = p & 31;
        int q00 = r * QS + q;
        int q01 = q00 + 1;
        int q10 = q00 + QS;
        int q11 = q10 + 1;

        float2 a0 = uph2(tnXY0[q11]);
        float2 a1 = uph2(tnXY0[q10]);
        float2 a2 = uph2(tnXY0[q01]);
        float2 b0 = uph2(tnXY1[q10]);
        float2 b1 = uph2(tnXY1[q00]);
        float2 b2 = uph2(tnXY1[q01]);
        float2 zA = uph2(tnZZ[q11]);
        float2 zB = uph2(tnZZ[q10]);
        float2 zC = uph2(tnZZ[q01]);
        float2 zD = uph2(tnZZ[q00]);

        float ax = a0.x + a1.x + a2.x + b0.x + b1.x + b2.x;
        float ay = a0.y + a1.y + a2.y + b0.y + b1.y + b2.y;
        float az = zA.x + zB.x + zC.x + zB.y + zD.y + zC.y;

        float d  = fmaxf(ax * ax + ay * ay + az * az, 1e-24f);
        float rs = fast_rsqrt(d) * sg;
        int gi = (fbn + (tr + r) * NSZ + (tq + q)) * 3;
        out2[gi + 0] = ax * rs;
        out2[gi + 1] = ay * rs;
        out2[gi + 2] = az * rs;
    }
}

extern "C" void kernel_launch(void* const* d_in, const int* in_sizes, int n_in,
                              void* d_out, int out_size, void* d_ws, size_t ws_size,
                              hipStream_t stream) {
    const float* vrt = (const float*)d_in[0];
    const float* nrm = (const float*)d_in[1];
    const float* ps  = (const float*)d_in[2];

    float* out0 = (float*)d_out;                 // vert:    6*512*512*3
    float* out1 = out0 + (size_t)NPIX * 3;       // faces:   NFACE*3
    float* out2 = out1 + (size_t)F3TOT;          // normals: 6*512*512*3

    k_all<<<GRID, 256, 0, stream>>>(vrt, nrm, ps, out0, out1, out2);
}

// Round 15
// 26.577 us; speedup vs baseline: 1.3672x; 1.0888x over previous
//
#include <hip/hip_runtime.h>
#include <math.h>

#define NSZ 512
#define MSZ 256
#define NPIX (6 * NSZ * NSZ)                      // 1,572,864 vertices
#define NQu  261121u                              // (NSZ-1)^2 quads per face
#define NQ2u 522242u                              // 2*NQu tris per face
#define NFACE 3133452                             // 6*2*NQu
#define F3TOT 9400356                             // NFACE*3 floats
#define NFT12 783363                              // F3TOT/12 (4 whole tris / thread)
#define TS 32                                     // output tile
#define HS 34                                     // vert halo
#define QS 33                                     // quad halo
#define NVB 1536                                  // 6*16*16 vert blocks
#define NFB ((NFT12 + 255) / 256)                 // 3061 faces blocks
#define GRID (NVB + NFB)

typedef __fp16 h2_t __attribute__((ext_vector_type(2)));

// ---- fast math helpers (raw HW op + 1 Newton step) -----------------------
__device__ inline float fast_rcp(float x) {
    float r = __builtin_amdgcn_rcpf(x);
    return r * (2.0f - x * r);
}
__device__ inline float fast_rsqrt(float d) {
    float r = __builtin_amdgcn_rsqf(d);
    return r * (1.5f - 0.5f * d * r * r);
}
__device__ inline float fast_sigmoid(float x) {
    float e = __builtin_amdgcn_exp2f(-1.442695040888963f * x);
    return fast_rcp(1.0f + e);
}
__device__ inline float lerpf(float a, float b, float w) {
    return __builtin_fmaf(w, b - a, a);
}
__device__ inline unsigned pkh2(float x, float y) {
    h2_t h = __builtin_amdgcn_cvt_pkrtz(x, y);
    return __builtin_bit_cast(unsigned, h);
}
__device__ inline float2 uph2(unsigned u) {
    h2_t h = __builtin_bit_cast(h2_t, u);
    return make_float2((float)h.x, (float)h.y);
}

__global__ __launch_bounds__(256) void k_all(const float* __restrict__ vrt,
                                             const float* __restrict__ nrm,
                                             const float* __restrict__ ps,
                                             float* __restrict__ out0,
                                             float* __restrict__ out1,
                                             float* __restrict__ out2) {
    // LDS: 13,872 + 3*4,356 = 26,940 B (R10 layout)
    __shared__ float sv[HS * HS * 3];         // displaced verts (halo), fp32
    __shared__ unsigned tnXY0[QS * QS];       // tri0 normal (x,y) fp16-packed
    __shared__ unsigned tnXY1[QS * QS];       // tri1 normal (x,y)
    __shared__ unsigned tnZZ [QS * QS];       // (z0, z1)

    int blk = blockIdx.x;

    if (blk >= NVB) {
        // ========== faces path: 12 floats = 4 whole tris / thread ==========
        int t = (blk - NVB) * 256 + threadIdx.x;
        if (t >= NFT12) return;
        unsigned tri = 4u * (unsigned)t;
        unsigned s   = tri / NQ2u;
        unsigned r1  = tri - s * NQ2u;
        unsigned ty  = (r1 >= NQu) ? 1u : 0u;
        unsigned qi  = r1 - ty * NQu;
        unsigned R   = qi / 511u;
        unsigned Q   = qi - R * 511u;

        unsigned a[4], tt[4];
        unsigned aq = Q, aR = R, aty = ty, as_ = s;
#pragma unroll
        for (int k = 0; k < 4; ++k) {
            a[k]  = (as_ << 18) + (aR << 9) + aq;
            tt[k] = aty;
            aq++;
            if (aq == 511u) {
                aq = 0u; aR++;
                if (aR == 511u) { aR = 0u; aty ^= 1u; if (aty == 0u) as_++; }
            }
        }
        float w[12];
#pragma unroll
        for (int k = 0; k < 4; ++k) {
            w[3*k + 0] = (float)(a[k] + (tt[k] ? 1u : 0u));
            w[3*k + 1] = (float)(a[k] + (tt[k] ? 513u : 1u));
            w[3*k + 2] = (float)(a[k] + 512u);
        }
        float4* o = (float4*)out1 + 3 * t;
        o[0] = make_float4(w[0], w[1], w[2],  w[3]);
        o[1] = make_float4(w[4], w[5], w[6],  w[7]);
        o[2] = make_float4(w[8], w[9], w[10], w[11]);
        return;
    }

    // ========== vert + normals path ==========
    int f   = blk >> 8;
    int tl  = blk & 255;
    int tr  = (tl >> 4) * TS;
    int tq  = (tl & 15) * TS;
    int fbm = f * (MSZ * MSZ);
    int fbn = f * (NSZ * NSZ);
    const float scale = 255.0f / 511.0f;

    // ---- phase 1: 34x34 halo -> sv (+ interior -> out0). ILP-unrolled: ----
    // items p = tid + 256k, k=0..3, plus guarded tail (1156 = 4*256 + 132).
    auto vert_item = [&](int p) {
        int pr = p / HS, pq = p - pr * HS;
        int y = tr + pr - 1, x = tq + pq - 1;
        int yc = min(max(y, 0), NSZ - 1);
        int xc = min(max(x, 0), NSZ - 1);

        float cy = (float)yc * scale;
        float cx = (float)xc * scale;
        int iy0 = min((int)cy, MSZ - 1);
        int ix0 = min((int)cx, MSZ - 1);
        float wy = cy - (float)iy0;
        float wx = cx - (float)ix0;
        int   iya = min(iy0, MSZ - 2);
        int   ixa = min(ix0, MSZ - 2);
        float wya = (iy0 < MSZ - 1) ? wy : 1.0f;
        float wxa = (ix0 < MSZ - 1) ? wx : 1.0f;

        int g0 = (fbm + iya * MSZ + ixa) * 3;     // row iya: 6 contiguous floats
        int g1 = g0 + MSZ * 3;                     // row iya+1

        float vx, vy, vz;
        {
            float a0 = vrt[g0], a1 = vrt[g0+1], a2 = vrt[g0+2];
            float a3 = vrt[g0+3], a4 = vrt[g0+4], a5 = vrt[g0+5];
            float b0 = vrt[g1], b1 = vrt[g1+1], b2 = vrt[g1+2];
            float b3 = vrt[g1+3], b4 = vrt[g1+4], b5 = vrt[g1+5];
            vx = lerpf(lerpf(a0, a3, wxa), lerpf(b0, b3, wxa), wya);
            vy = lerpf(lerpf(a1, a4, wxa), lerpf(b1, b4, wxa), wya);
            vz = lerpf(lerpf(a2, a5, wxa), lerpf(b2, b5, wxa), wya);
        }
        float nx, ny, nz;
        {
            float a0 = nrm[g0], a1 = nrm[g0+1], a2 = nrm[g0+2];
            float a3 = nrm[g0+3], a4 = nrm[g0+4], a5 = nrm[g0+5];
            float b0 = nrm[g1], b1 = nrm[g1+1], b2 = nrm[g1+2];
            float b3 = nrm[g1+3], b4 = nrm[g1+4], b5 = nrm[g1+5];
            nx = lerpf(lerpf(a0, a3, wxa), lerpf(b0, b3, wxa), wya);
            ny = lerpf(lerpf(a1, a4, wxa), lerpf(b1, b4, wxa), wya);
            nz = lerpf(lerpf(a2, a5, wxa), lerpf(b2, b5, wxa), wya);
        }

        float mag = __builtin_amdgcn_sqrtf(nx * nx + ny * ny + nz * nz);
        float sig = fast_sigmoid(ps[fbn + yc * NSZ + xc]);
        float add = 0.5f * sig * mag;
        float ox = vx + add, oy = vy + add, oz = vz + add;

        sv[p * 3 + 0] = ox;
        sv[p * 3 + 1] = oy;
        sv[p * 3 + 2] = oz;
        if (pr >= 1 && pr <= TS && pq >= 1 && pq <= TS) {
            int gi = (fbn + y * NSZ + x) * 3;
            out0[gi + 0] = ox;
            out0[gi + 1] = oy;
            out0[gi + 2] = oz;
        }
    };
    {
        int tid = threadIdx.x;
#pragma unroll
        for (int k = 0; k < 4; ++k) vert_item(tid + 256 * k);
        if (tid < HS * HS - 1024) vert_item(tid + 1024);   // tail: 132 items
    }
    __syncthreads();

    // ---- phase 1.5: 33x33 quads' 2 tri unit normals, ONCE, fp16-packed ----
    // ILP-unrolled: 1089 = 4*256 + 65.
    auto quad_item = [&](int p) {
        int Ri = p / QS, Qi = p - Ri * QS;
        int base = (Ri * HS + Qi) * 3;
        float Axx = sv[base + 0],        Axy = sv[base + 1],        Axz = sv[base + 2];
        float Bxx = sv[base + 3],        Bxy = sv[base + 4],        Bxz = sv[base + 5];
        float Cxx = sv[base + HS*3 + 0], Cxy = sv[base + HS*3 + 1], Cxz = sv[base + HS*3 + 2];
        float Dxx = sv[base + HS*3 + 3], Dxy = sv[base + HS*3 + 4], Dxz = sv[base + HS*3 + 5];

        float n0x, n0y, n0z;
        {   // tri0: (A, B, C)
            float e1x = Bxx - Axx, e1y = Bxy - Axy, e1z = Bxz - Axz;
            float e2x = Cxx - Axx, e2y = Cxy - Axy, e2z = Cxz - Axz;
            float cx = e1y * e2z - e1z * e2y;
            float cy = e1z * e2x - e1x * e2z;
            float cz = e1x * e2y - e1y * e2x;
            float d  = fmaxf(cx * cx + cy * cy + cz * cz, 1e-24f);
            float r  = fast_rsqrt(d);
            n0x = cx * r; n0y = cy * r; n0z = cz * r;
        }
        float n1x, n1y, n1z;
        {   // tri1: (B, D, C)
            float e1x = Dxx - Bxx, e1y = Dxy - Bxy, e1z = Dxz - Bxz;
            float e2x = Cxx - Bxx, e2y = Cxy - Bxy, e2z = Cxz - Bxz;
            float cx = e1y * e2z - e1z * e2y;
            float cy = e1z * e2x - e1x * e2z;
            float cz = e1x * e2y - e1y * e2x;
            float d  = fmaxf(cx * cx + cy * cy + cz * cz, 1e-24f);
            float r  = fast_rsqrt(d);
            n1x = cx * r; n1y = cy * r; n1z = cz * r;
        }
        tnXY0[p] = pkh2(n0x, n0y);
        tnXY1[p] = pkh2(n1x, n1y);
        tnZZ [p] = pkh2(n0z, n1z);
    };
    {
        int tid = threadIdx.x;
#pragma unroll
        for (int k = 0; k < 4; ++k) quad_item(tid + 256 * k);
        if (tid < QS * QS - 1024) quad_item(tid + 1024);   // tail: 65 items
    }
    __syncthreads();

    // ---- phase 2: vertex normals, exactly 4 items/thread ----
    float sg = (f == 1 || f == 2 || f == 5) ? 1.0f : -1.0f;
    auto norm_item = [&](int p) {
        int r = p >> 5, q = p & 31;
        int q00 = r * QS + q;
        int q01 = q00 + 1;
        int q10 = q00 + QS;
        int q11 = q10 + 1;

        float2 a0 = uph2(tnXY0[q11]);
        float2 a1 = uph2(tnXY0[q10]);
        float2 a2 = uph2(tnXY0[q01]);
        float2 b0 = uph2(tnXY1[q10]);
        float2 b1 = uph2(tnXY1[q00]);
        float2 b2 = uph2(tnXY1[q01]);
        float2 zA = uph2(tnZZ[q11]);
        float2 zB = uph2(tnZZ[q10]);
        float2 zC = uph2(tnZZ[q01]);
        float2 zD = uph2(tnZZ[q00]);

        float ax = a0.x + a1.x + a2.x + b0.x + b1.x + b2.x;
        float ay = a0.y + a1.y + a2.y + b0.y + b1.y + b2.y;
        float az = zA.x + zB.x + zC.x + zB.y + zD.y + zC.y;

        float d  = fmaxf(ax * ax + ay * ay + az * az, 1e-24f);
        float rs = fast_rsqrt(d) * sg;
        int gi = (fbn + (tr + r) * NSZ + (tq + q)) * 3;
        out2[gi + 0] = ax * rs;
        out2[gi + 1] = ay * rs;
        out2[gi + 2] = az * rs;
    };
    {
        int tid = threadIdx.x;
#pragma unroll
        for (int k = 0; k < 4; ++k) norm_item(tid + 256 * k);
    }
}

extern "C" void kernel_launch(void* const* d_in, const int* in_sizes, int n_in,
                              void* d_out, int out_size, void* d_ws, size_t ws_size,
                              hipStream_t stream) {
    const float* vrt = (const float*)d_in[0];
    const float* nrm = (const float*)d_in[1];
    const float* ps  = (const float*)d_in[2];

    float* out0 = (float*)d_out;                 // vert:    6*512*512*3
    float* out1 = out0 + (size_t)NPIX * 3;       // faces:   NFACE*3
    float* out2 = out1 + (size_t)F3TOT;          // normals: 6*512*512*3

    k_all<<<GRID, 256, 0, stream>>>(vrt, nrm, ps, out0, out1, out2);
}